// Round 9
// baseline (259.117 us; speedup 1.0000x reference)
//
#include <hip/hip_runtime.h>
#include <stdint.h>
#include <math.h>

// Problem constants (B,L,H,D fixed by setup_inputs)
#define Bn 4
#define Ln 2048
#define Hn 8
#define Dn 64
#define BHn (Bn*Hn)
#define NTOP 40   // FACTOR * ceil(log(2048)) = 5*8
#define SK   40
#define NSAMP (Ln*SK)        // 81920

// ---------------- Threefry-2x32 (exact JAX replication) ----------------
__host__ __device__ inline uint32_t rotl32(uint32_t x, int r) {
  return (x << r) | (x >> (32 - r));
}

__host__ __device__ inline void tf2x32(uint32_t k0, uint32_t k1,
                                       uint32_t& x0, uint32_t& x1) {
  const uint32_t ks2 = k0 ^ k1 ^ 0x1BD11BDAu;
  const int RA[4] = {13, 15, 26, 6};
  const int RB[4] = {17, 29, 16, 24};
  x0 += k0; x1 += k1;
  for (int i = 0; i < 4; i++) { x0 += x1; x1 = rotl32(x1, RA[i]); x1 ^= x0; }
  x0 += k1;  x1 += ks2 + 1u;
  for (int i = 0; i < 4; i++) { x0 += x1; x1 = rotl32(x1, RB[i]); x1 ^= x0; }
  x0 += ks2; x1 += k0 + 2u;
  for (int i = 0; i < 4; i++) { x0 += x1; x1 = rotl32(x1, RA[i]); x1 ^= x0; }
  x0 += k0;  x1 += k1 + 3u;
  for (int i = 0; i < 4; i++) { x0 += x1; x1 = rotl32(x1, RB[i]); x1 ^= x0; }
  x0 += k1;  x1 += ks2 + 4u;
  for (int i = 0; i < 4; i++) { x0 += x1; x1 = rotl32(x1, RA[i]); x1 ^= x0; }
  x0 += ks2; x1 += k0 + 5u;
}

// jax_threefry_partitionable=True: elem j -> ctr (0, j); draw = out0 ^ out1
__global__ void gen_samples(int* __restrict__ sample, uint32_t k0, uint32_t k1) {
  int j = blockIdx.x * blockDim.x + threadIdx.x;
  if (j >= NSAMP) return;
  uint32_t x0 = 0u, x1 = (uint32_t)j;
  tf2x32(k0, k1, x0, x1);
  sample[j] = (int)((x0 ^ x1) & (Ln - 1));
}

// ---------------- M = max_s(QK_s) - sum_s(QK_s)/L ----------------
// v2 (proven R7): quarter-wave-cooperative coalesced gather.
__global__ __launch_bounds__(256) void compute_M(const float* __restrict__ Q,
                                                 const float* __restrict__ K,
                                                 const int* __restrict__ sample,
                                                 float* __restrict__ M) {
  int xcd = blockIdx.x & 7;
  int idx = blockIdx.x >> 3;          // 0..511
  int bh  = (idx & 3) * 8 + xcd;      // {xcd, xcd+8, xcd+16, xcd+24}
  int seg = idx >> 2;                 // 0..127
  int tid = threadIdx.x;
  int qw  = tid >> 4;                 // quarter-wave id in wg: 0..15
  int j   = tid & 15;                 // lane within quarter-wave
  int i   = seg * 16 + qw;            // query index
  int wl  = tid & 63;                 // lane within wave
  int qbase = wl & 48;                // first lane of this quarter-wave

  const float* Qb = Q + ((size_t)bh * Ln + i) * Dn;
  float4 qf = ((const float4*)Qb)[j];

  const int* smp = sample + (size_t)i * SK;
  int s0 = smp[j];
  int s1 = smp[16 + j];
  int s2 = smp[32 + (j & 7)];

  const float* Kb = K + (size_t)bh * Ln * Dn;
  float mx = -INFINITY, sm = 0.f;
#pragma unroll
  for (int s = 0; s < SK; s++) {
    int sreg = (s < 16) ? s0 : (s < 32 ? s1 : s2);
    int l = __shfl(sreg, qbase | (s & 15), 64);
    float4 kf = ((const float4*)(Kb + (size_t)l * Dn))[j];
    float d = qf.x * kf.x + qf.y * kf.y + qf.z * kf.z + qf.w * kf.w;
    d += __shfl_xor(d, 1, 64);
    d += __shfl_xor(d, 2, 64);
    d += __shfl_xor(d, 4, 64);
    d += __shfl_xor(d, 8, 64);
    mx = fmaxf(mx, d);
    sm += d;                           // full dot in every lane; sum ok
  }
  if (j == 0)
    M[(size_t)bh * Ln + i] = mx - sm * (1.0f / (float)Ln);
}

// ---------------- top-40: stage 1, single wave per 256-segment ----------------
__global__ __launch_bounds__(64) void topk_stage1(const float* __restrict__ M,
                                                  float* __restrict__ cval,
                                                  int* __restrict__ cidx) {
  int bh = blockIdx.x >> 3, seg = blockIdx.x & 7;
  int lane = threadIdx.x;
  float cur[4];
  const float* m = M + (size_t)bh * Ln + seg * 256;
#pragma unroll
  for (int j = 0; j < 4; j++) cur[j] = m[lane + 64 * j];
  for (int k = 0; k < NTOP; ++k) {
    float bv = cur[0]; int bj = 0;
#pragma unroll
    for (int j = 1; j < 4; j++)
      if (cur[j] > bv) { bv = cur[j]; bj = j; }   // ascending j: ties keep smaller
    int bi = lane + 64 * bj;
#pragma unroll
    for (int off = 1; off < 64; off <<= 1) {
      float ov = __shfl_xor(bv, off, 64);
      int   oi = __shfl_xor(bi, off, 64);
      if (ov > bv || (ov == bv && oi < bi)) { bv = ov; bi = oi; }
    }
    if (lane == 0) {
      cval[blockIdx.x * NTOP + k] = bv;
      cidx[blockIdx.x * NTOP + k] = seg * 256 + bi;
    }
    int wl = bi & 63, wj = bi >> 6;
    if (lane == wl) cur[wj] = -INFINITY;
  }
}

// ---------------- top-40: stage 2, single wave merges 320 candidates ----------------
__global__ __launch_bounds__(64) void topk_stage2(const float* __restrict__ cval,
                                                  const int* __restrict__ cidx,
                                                  int* __restrict__ Mtop) {
  int bh = blockIdx.x;
  int lane = threadIdx.x;
  float cur[5]; int gix[5];
#pragma unroll
  for (int j = 0; j < 5; j++) {
    cur[j] = cval[bh * 320 + lane + 64 * j];
    gix[j] = cidx[bh * 320 + lane + 64 * j];
  }
  for (int k = 0; k < NTOP; ++k) {
    float bv = cur[0]; int bg = gix[0];
#pragma unroll
    for (int j = 1; j < 5; j++)
      if (cur[j] > bv || (cur[j] == bv && gix[j] < bg)) { bv = cur[j]; bg = gix[j]; }
#pragma unroll
    for (int off = 1; off < 64; off <<= 1) {
      float ov = __shfl_xor(bv, off, 64);
      int   og = __shfl_xor(bg, off, 64);
      if (ov > bv || (ov == bv && og < bg)) { bv = ov; bg = og; }
    }
    if (lane == 0) Mtop[bh * NTOP + k] = bg;
#pragma unroll
    for (int j = 0; j < 5; j++)
      if (gix[j] == bg) cur[j] = -INFINITY;
  }
}

// ---------------- context cumsum, phase 1: per-tile (64 l) sums ----------------
__global__ __launch_bounds__(256) void vsum_partial(const float* __restrict__ V,
                                                    float* __restrict__ partial) {
  int tile = blockIdx.x & 31;
  int bh   = blockIdx.x >> 5;
  int d = threadIdx.x & 63;
  int g = threadIdx.x >> 6;
  const float* Vb = V + (size_t)bh * Ln * Dn;
  int l0 = tile * 64 + g * 16;
  float s = 0.f;
  for (int j = 0; j < 16; j++) s += Vb[(size_t)(l0 + j) * Dn + d];
  __shared__ float red[4][64];
  red[g][d] = s;
  __syncthreads();
  if (g == 0)
    partial[((size_t)bh * 32 + tile) * 64 + d] =
        red[0][d] + red[1][d] + red[2][d] + red[3][d];
}

// ---------------- context cumsum, phase 2: prefix + cumsum + transposed write ----------------
__global__ __launch_bounds__(256) void context_write(const float* __restrict__ V,
                                                     const float* __restrict__ partial,
                                                     float* __restrict__ out) {
  int tile = blockIdx.x & 31;
  int bh   = blockIdx.x >> 5;
  int b = bh >> 3, h = bh & 7;
  int d = threadIdx.x & 63;
  int g = threadIdx.x >> 6;
  __shared__ float red[4][64];
  float p = 0.f;
  for (int t = g; t < tile; t += 4)
    p += partial[((size_t)bh * 32 + t) * 64 + d];
  red[g][d] = p;
  __syncthreads();
  float prefix = red[0][d] + red[1][d] + red[2][d] + red[3][d];
  __syncthreads();
  const float* Vb = V + (size_t)bh * Ln * Dn;
  int l0 = tile * 64 + g * 16;
  float vloc[16]; float s = 0.f;
  for (int j = 0; j < 16; j++) {
    vloc[j] = Vb[(size_t)(l0 + j) * Dn + d];
    s += vloc[j];
  }
  red[g][d] = s;
  __syncthreads();
  float running = prefix;
  for (int gg = 0; gg < g; gg++) running += red[gg][d];
  for (int j = 0; j < 16; j++) {
    int l = l0 + j;
    running += vloc[j];
    out[(((size_t)b * Ln + l) * Hn + h) * Dn + d] =
        0.5f * ((float)(l + 1) * vloc[j] + running);
  }
}

// ---------------- sparse attention over the 40 selected rows ----------------
// Pass 1 v2: transposed loads. Wave w owns rows [w*256, w*256+256); lane =
// (quad,lr): one float4 load = 4 full rows (~8 cache lines vs 64 with the
// old l=tid+j*512 mapping — the TA line-lookup serialization that cost
// ~27 of 52 us). Dot = 4-wide lane partial vs register-hoisted qs/ks
// fragments + 4 shfl_xor quad-reduce; lane quad==u writes masked score.
#define UC 5
__global__ __launch_bounds__(512, 2) void sparse_attn(const float* __restrict__ Q,
                                                      const float* __restrict__ K,
                                                      const float* __restrict__ V,
                                                      const int* __restrict__ Mtop,
                                                      float* __restrict__ out) {
  int xcd  = blockIdx.x & 7;
  int rest = blockIdx.x >> 3;     // 0..31
  int chunk = rest & 7;
  int bh    = (rest >> 3) * 8 + xcd;
  int b = bh >> 3, h = bh & 7;
  __shared__ alignas(16) float sc[UC][Ln];           // 40 KB scores->probs
  __shared__ alignas(16) float qs[UC][Dn];
  __shared__ alignas(16) float ks[UC][Dn];
  __shared__ float vs[UC][Dn];
  __shared__ alignas(16) float redp[8][UC][64];      // 10 KB partial attn@V
  __shared__ int   rows_s[UC];
  __shared__ float inv_s[UC];
  const float* Qb = Q + (size_t)bh * Ln * Dn;
  const float* Kb = K + (size_t)bh * Ln * Dn;
  const float* Vb = V + (size_t)bh * Ln * Dn;
  int tid = threadIdx.x;

  if (tid < UC * 64) {
    int u = tid >> 6, d = tid & 63;
    int row = Mtop[bh * NTOP + chunk * UC + u];
    if (d == 0) rows_s[u] = row;
    qs[u][d] = Qb[(size_t)row * Dn + d];
    ks[u][d] = Kb[(size_t)row * Dn + d];
    vs[u][d] = Vb[(size_t)row * Dn + d];
  }
  __syncthreads();

  int w = tid >> 6, lane = tid & 63;
  int quad = lane & 15, lr = lane >> 4;

  // pass 1: wave w computes sc[u][l] for l in [w*256, w*256+256), all 5 u
  {
    const float4* K4 = (const float4*)Kb;
    const float4* Q4 = (const float4*)Qb;
    float4 qs4[UC], ks4[UC];
    int ru[UC];
#pragma unroll
    for (int u = 0; u < UC; u++) {
      qs4[u] = *(const float4*)(&qs[u][quad * 4]);
      ks4[u] = *(const float4*)(&ks[u][quad * 4]);
      ru[u] = rows_s[u];
    }
    int rowbase = w * 256 + lr;
    for (int g = 0; g < 64; g += 4) {
      float4 kf[4], qf[4];
#pragma unroll
      for (int x = 0; x < 4; x++) {
        int row = rowbase + (g + x) * 4;
        kf[x] = K4[(size_t)row * 16 + quad];
        qf[x] = Q4[(size_t)row * 16 + quad];
      }
#pragma unroll
      for (int x = 0; x < 4; x++) {
        int l = rowbase + (g + x) * 4;
#pragma unroll
        for (int u = 0; u < UC; u++) {
          float d = qs4[u].x * kf[x].x + qs4[u].y * kf[x].y
                  + qs4[u].z * kf[x].z + qs4[u].w * kf[x].w
                  + ks4[u].x * qf[x].x + ks4[u].y * qf[x].y
                  + ks4[u].z * qf[x].z + ks4[u].w * qf[x].w;
          d += __shfl_xor(d, 1, 64);
          d += __shfl_xor(d, 2, 64);
          d += __shfl_xor(d, 4, 64);
          d += __shfl_xor(d, 8, 64);
          if (quad == u) sc[u][l] = (l > ru[u]) ? -1e9f : d * 0.0625f;
        }
      }
    }
  }
  __syncthreads();

  // pass 2: softmax per u; wave w handles u=w (waves 0..4)
  if (w < UC) {
    float mx = -INFINITY;
    for (int kq = 0; kq < 32; kq++) mx = fmaxf(mx, sc[w][lane + 64 * kq]);
    for (int off = 32; off; off >>= 1) mx = fmaxf(mx, __shfl_xor(mx, off, 64));
    float sum = 0.f;
    for (int kq = 0; kq < 32; kq++) {
      float e = __expf(sc[w][lane + 64 * kq] - mx);
      sc[w][lane + 64 * kq] = e;
      sum += e;
    }
    for (int off = 32; off; off >>= 1) sum += __shfl_xor(sum, off, 64);
    if (lane == 0) inv_s[w] = 1.0f / sum;
  }
  __syncthreads();

  // pass 3: attn @ V ; wave w owns l in [w*256, w*256+256) for ALL 5 u.
  {
    int l0w = w * 256;
    const float4* V4 = (const float4*)Vb;
    float4 a[UC];
#pragma unroll
    for (int u = 0; u < UC; u++) a[u] = make_float4(0.f, 0.f, 0.f, 0.f);
    for (int it4 = 0; it4 < 16; it4++) {
      int lb = l0w + lr + it4 * 16;
      float4 v0 = V4[(size_t)(lb)      * 16 + quad];
      float4 v1 = V4[(size_t)(lb + 4)  * 16 + quad];
      float4 v2 = V4[(size_t)(lb + 8)  * 16 + quad];
      float4 v3 = V4[(size_t)(lb + 12) * 16 + quad];
#pragma unroll
      for (int u = 0; u < UC; u++) {
        float s0 = sc[u][lb], s1 = sc[u][lb + 4], s2 = sc[u][lb + 8], s3 = sc[u][lb + 12];
        a[u].x += s0 * v0.x + s1 * v1.x + s2 * v2.x + s3 * v3.x;
        a[u].y += s0 * v0.y + s1 * v1.y + s2 * v2.y + s3 * v3.y;
        a[u].z += s0 * v0.z + s1 * v1.z + s2 * v2.z + s3 * v3.z;
        a[u].w += s0 * v0.w + s1 * v1.w + s2 * v2.w + s3 * v3.w;
      }
    }
#pragma unroll
    for (int u = 0; u < UC; u++) {
#pragma unroll
      for (int off = 16; off < 64; off <<= 1) {
        a[u].x += __shfl_xor(a[u].x, off, 64);
        a[u].y += __shfl_xor(a[u].y, off, 64);
        a[u].z += __shfl_xor(a[u].z, off, 64);
        a[u].w += __shfl_xor(a[u].w, off, 64);
      }
      if (lr == 0) *(float4*)(&redp[w][u][quad * 4]) = a[u];
    }
  }
  __syncthreads();

  if (w < UC) {
    float r = 0.f;
#pragma unroll
    for (int g = 0; g < 8; g++) r += redp[g][w][lane];
    float outv = 0.5f * (vs[w][lane] + r * inv_s[w]);
    int row = rows_s[w];
    out[(((size_t)b * Ln + row) * Hn + h) * Dn + lane] = outv;
  }
}

extern "C" void kernel_launch(void* const* d_in, const int* in_sizes, int n_in,
                              void* d_out, int out_size, void* d_ws, size_t ws_size,
                              hipStream_t stream) {
  const float* Q = (const float*)d_in[0];  // (B,L,H,D) flat == (B,H,L,D) reshape
  const float* K = (const float*)d_in[1];
  const float* V = (const float*)d_in[2];
  float* out = (float*)d_out;
  char* ws = (char*)d_ws;

  int*   sample  = (int*)ws;                                       // 320 KB
  float* M       = (float*)(ws + NSAMP * 4);                       // 256 KB
  int*   Mtop    = (int*)(ws + NSAMP * 4 + BHn * Ln * 4);          // 5 KB
  float* partial = (float*)(ws + NSAMP * 4 + BHn * Ln * 4 + BHn * NTOP * 4); // 256 KB
  // cval/cidx alias the sample region: sample is dead after compute_M,
  // and kernels on one stream serialize, so this is race-free.
  float* cval = (float*)ws;                       // 40 KB (BHn*8*NTOP)
  int*   cidx = (int*)(ws + BHn * 8 * NTOP * 4);  // 40 KB

  // Partitionable threefry split of key(42) = (0,42): k2 = tf(key, ctr=(0,1)).
  uint32_t s0 = 0u, s1 = 1u;
  tf2x32(0u, 42u, s0, s1);

  gen_samples<<<NSAMP / 256, 256, 0, stream>>>(sample, s0, s1);
  compute_M<<<4096, 256, 0, stream>>>(Q, K, sample, M);
  topk_stage1<<<BHn * 8, 64, 0, stream>>>(M, cval, cidx);
  topk_stage2<<<BHn, 64, 0, stream>>>(cval, cidx, Mtop);
  vsum_partial<<<BHn * 32, 256, 0, stream>>>(V, partial);
  context_write<<<BHn * 32, 256, 0, stream>>>(V, partial, out);
  sparse_attn<<<BHn * 8, 512, 0, stream>>>(Q, K, V, Mtop, out);
}

// Round 10
// 234.569 us; speedup vs baseline: 1.1047x; 1.1047x over previous
//
#include <hip/hip_runtime.h>
#include <stdint.h>
#include <math.h>

// Problem constants (B,L,H,D fixed by setup_inputs)
#define Bn 4
#define Ln 2048
#define Hn 8
#define Dn 64
#define BHn (Bn*Hn)
#define NTOP 40   // FACTOR * ceil(log(2048)) = 5*8
#define SK   40
#define NSAMP (Ln*SK)        // 81920

// ---------------- Threefry-2x32 (exact JAX replication) ----------------
__host__ __device__ inline uint32_t rotl32(uint32_t x, int r) {
  return (x << r) | (x >> (32 - r));
}

__host__ __device__ inline void tf2x32(uint32_t k0, uint32_t k1,
                                       uint32_t& x0, uint32_t& x1) {
  const uint32_t ks2 = k0 ^ k1 ^ 0x1BD11BDAu;
  const int RA[4] = {13, 15, 26, 6};
  const int RB[4] = {17, 29, 16, 24};
  x0 += k0; x1 += k1;
  for (int i = 0; i < 4; i++) { x0 += x1; x1 = rotl32(x1, RA[i]); x1 ^= x0; }
  x0 += k1;  x1 += ks2 + 1u;
  for (int i = 0; i < 4; i++) { x0 += x1; x1 = rotl32(x1, RB[i]); x1 ^= x0; }
  x0 += ks2; x1 += k0 + 2u;
  for (int i = 0; i < 4; i++) { x0 += x1; x1 = rotl32(x1, RA[i]); x1 ^= x0; }
  x0 += k0;  x1 += k1 + 3u;
  for (int i = 0; i < 4; i++) { x0 += x1; x1 = rotl32(x1, RB[i]); x1 ^= x0; }
  x0 += k1;  x1 += ks2 + 4u;
  for (int i = 0; i < 4; i++) { x0 += x1; x1 = rotl32(x1, RA[i]); x1 ^= x0; }
  x0 += ks2; x1 += k0 + 5u;
}

// jax_threefry_partitionable=True: elem n -> ctr (0, n); draw = out0 ^ out1
__device__ inline int draw2048(uint32_t k0, uint32_t k1, uint32_t n) {
  uint32_t a = 0u, b = n;
  tf2x32(k0, k1, a, b);
  return (int)((a ^ b) & (Ln - 1));
}

// ---------------- M = max_s(QK_s) - sum_s(QK_s)/L ----------------
// v2 (proven R7) + fused sample generation: quarter-wave-cooperative
// coalesced gather; each lane inlines its 3 threefry draws (~180 VALU)
// instead of reading sample[] (kills the gen_samples dispatch + traffic).
__global__ __launch_bounds__(256) void compute_M(const float* __restrict__ Q,
                                                 const float* __restrict__ K,
                                                 float* __restrict__ M,
                                                 uint32_t k0, uint32_t k1) {
  int xcd = blockIdx.x & 7;
  int idx = blockIdx.x >> 3;          // 0..511
  int bh  = (idx & 3) * 8 + xcd;      // {xcd, xcd+8, xcd+16, xcd+24}
  int seg = idx >> 2;                 // 0..127
  int tid = threadIdx.x;
  int qw  = tid >> 4;                 // quarter-wave id in wg: 0..15
  int j   = tid & 15;                 // lane within quarter-wave
  int i   = seg * 16 + qw;            // query index
  int wl  = tid & 63;                 // lane within wave
  int qbase = wl & 48;                // first lane of this quarter-wave

  const float* Qb = Q + ((size_t)bh * Ln + i) * Dn;
  float4 qf = ((const float4*)Qb)[j];

  uint32_t n0 = (uint32_t)(i * SK);
  int s0 = draw2048(k0, k1, n0 + j);
  int s1 = draw2048(k0, k1, n0 + 16 + j);
  int s2 = draw2048(k0, k1, n0 + 32 + (j & 7));

  const float* Kb = K + (size_t)bh * Ln * Dn;
  float mx = -INFINITY, sm = 0.f;
#pragma unroll
  for (int s = 0; s < SK; s++) {
    int sreg = (s < 16) ? s0 : (s < 32 ? s1 : s2);
    int l = __shfl(sreg, qbase | (s & 15), 64);
    float4 kf = ((const float4*)(Kb + (size_t)l * Dn))[j];
    float d = qf.x * kf.x + qf.y * kf.y + qf.z * kf.z + qf.w * kf.w;
    d += __shfl_xor(d, 1, 64);
    d += __shfl_xor(d, 2, 64);
    d += __shfl_xor(d, 4, 64);
    d += __shfl_xor(d, 8, 64);
    mx = fmaxf(mx, d);
    sm += d;                           // full dot in every lane; sum ok
  }
  if (j == 0)
    M[(size_t)bh * Ln + i] = mx - sm * (1.0f / (float)Ln);
}

// ---------------- top-40, fused: one wg (4 waves) per bh ----------------
// Wave w: exact top-40 of its 512-element segment (8 vals/lane in regs,
// pure shfl argmax, global-index tie-break) -> LDS. Wave 0 merges the
// 4*40=160 candidates. Correct because the global top-40 elements are each
// inside their segment's top-40; tie-break lexicographic on global index
// matches jax.lax.top_k.
__global__ __launch_bounds__(256) void topk_fused(const float* __restrict__ M,
                                                  int* __restrict__ Mtop) {
  int bh = blockIdx.x;
  int tid = threadIdx.x, lane = tid & 63, w = tid >> 6;
  __shared__ float cv[4][NTOP];
  __shared__ int   ci[4][NTOP];
  {
    float cur[8];
    const float* m = M + (size_t)bh * Ln + w * 512;
#pragma unroll
    for (int j = 0; j < 8; j++) cur[j] = m[lane + 64 * j];
    for (int k = 0; k < NTOP; ++k) {
      float bv = cur[0]; int bj = 0;
#pragma unroll
      for (int j = 1; j < 8; j++)
        if (cur[j] > bv) { bv = cur[j]; bj = j; }  // ties keep smaller j
      int bi = w * 512 + lane + 64 * bj;           // bh-local global index
#pragma unroll
      for (int off = 1; off < 64; off <<= 1) {
        float ov = __shfl_xor(bv, off, 64);
        int   oi = __shfl_xor(bi, off, 64);
        if (ov > bv || (ov == bv && oi < bi)) { bv = ov; bi = oi; }
      }
      if (lane == 0) { cv[w][k] = bv; ci[w][k] = bi; }
      int wl2 = (bi >> 6) & 7;  // (bi - w*512)/64 ... decompose below
      int ll  = bi & 63;
      // bi = w*512 + lane + 64*j -> j = ((bi - w*512) >> 6)
      int jj = (bi - w * 512) >> 6;
      (void)wl2;
      if (lane == ll) cur[jj] = -INFINITY;
    }
  }
  __syncthreads();
  if (w == 0) {
    float cur[3]; int gix[3];
#pragma unroll
    for (int j = 0; j < 3; j++) {
      int c = lane + 64 * j;
      if (c < 160) { cur[j] = cv[c / NTOP][c % NTOP]; gix[j] = ci[c / NTOP][c % NTOP]; }
      else         { cur[j] = -INFINITY; gix[j] = 0x7fffffff; }
    }
    for (int k = 0; k < NTOP; ++k) {
      float bv = cur[0]; int bg = gix[0];
#pragma unroll
      for (int j = 1; j < 3; j++)
        if (cur[j] > bv || (cur[j] == bv && gix[j] < bg)) { bv = cur[j]; bg = gix[j]; }
#pragma unroll
      for (int off = 1; off < 64; off <<= 1) {
        float ov = __shfl_xor(bv, off, 64);
        int   og = __shfl_xor(bg, off, 64);
        if (ov > bv || (ov == bv && og < bg)) { bv = ov; bg = og; }
      }
      if (lane == 0) Mtop[bh * NTOP + k] = bg;
#pragma unroll
      for (int j = 0; j < 3; j++)
        if (gix[j] == bg) cur[j] = -INFINITY;
    }
  }
}

// ---------------- context cumsum, phase 1: per-tile (64 l) sums ----------------
__global__ __launch_bounds__(256) void vsum_partial(const float* __restrict__ V,
                                                    float* __restrict__ partial) {
  int tile = blockIdx.x & 31;
  int bh   = blockIdx.x >> 5;
  int d = threadIdx.x & 63;
  int g = threadIdx.x >> 6;
  const float* Vb = V + (size_t)bh * Ln * Dn;
  int l0 = tile * 64 + g * 16;
  float s = 0.f;
  for (int j = 0; j < 16; j++) s += Vb[(size_t)(l0 + j) * Dn + d];
  __shared__ float red[4][64];
  red[g][d] = s;
  __syncthreads();
  if (g == 0)
    partial[((size_t)bh * 32 + tile) * 64 + d] =
        red[0][d] + red[1][d] + red[2][d] + red[3][d];
}

// ---------------- context cumsum, phase 2: prefix + cumsum + transposed write ----------------
__global__ __launch_bounds__(256) void context_write(const float* __restrict__ V,
                                                     const float* __restrict__ partial,
                                                     float* __restrict__ out) {
  int tile = blockIdx.x & 31;
  int bh   = blockIdx.x >> 5;
  int b = bh >> 3, h = bh & 7;
  int d = threadIdx.x & 63;
  int g = threadIdx.x >> 6;
  __shared__ float red[4][64];
  float p = 0.f;
  for (int t = g; t < tile; t += 4)
    p += partial[((size_t)bh * 32 + t) * 64 + d];
  red[g][d] = p;
  __syncthreads();
  float prefix = red[0][d] + red[1][d] + red[2][d] + red[3][d];
  __syncthreads();
  const float* Vb = V + (size_t)bh * Ln * Dn;
  int l0 = tile * 64 + g * 16;
  float vloc[16]; float s = 0.f;
  for (int j = 0; j < 16; j++) {
    vloc[j] = Vb[(size_t)(l0 + j) * Dn + d];
    s += vloc[j];
  }
  red[g][d] = s;
  __syncthreads();
  float running = prefix;
  for (int gg = 0; gg < g; gg++) running += red[gg][d];
  for (int j = 0; j < 16; j++) {
    int l = l0 + j;
    running += vloc[j];
    out[(((size_t)b * Ln + l) * Hn + h) * Dn + d] =
        0.5f * ((float)(l + 1) * vloc[j] + running);
  }
}

// ---------------- sparse attention over the 40 selected rows ----------------
// PROVEN R6 version (52 us): R3 pass1 (streaming loads, pure register
// accumulation — NO per-dot shfl; R8's shfl-reduce variant regressed to
// 74 us by saturating the DS pipe) + float4-V pass3. XCD swizzle: all 8
// chunks of one bh share an XCD.
#define UC 5
__global__ __launch_bounds__(512, 2) void sparse_attn(const float* __restrict__ Q,
                                                      const float* __restrict__ K,
                                                      const float* __restrict__ V,
                                                      const int* __restrict__ Mtop,
                                                      float* __restrict__ out) {
  int xcd  = blockIdx.x & 7;
  int rest = blockIdx.x >> 3;     // 0..31
  int chunk = rest & 7;
  int bh    = (rest >> 3) * 8 + xcd;
  int b = bh >> 3, h = bh & 7;
  __shared__ alignas(16) float sc[UC][Ln];           // 40 KB scores->probs
  __shared__ alignas(16) float qs[UC][Dn];
  __shared__ alignas(16) float ks[UC][Dn];
  __shared__ float vs[UC][Dn];
  __shared__ alignas(16) float redp[8][UC][64];      // 10 KB partial attn@V
  __shared__ int   rows_s[UC];
  __shared__ float inv_s[UC];
  const float* Qb = Q + (size_t)bh * Ln * Dn;
  const float* Kb = K + (size_t)bh * Ln * Dn;
  const float* Vb = V + (size_t)bh * Ln * Dn;
  int tid = threadIdx.x;

  if (tid < UC * 64) {
    int u = tid >> 6, d = tid & 63;
    int row = Mtop[bh * NTOP + chunk * UC + u];
    if (d == 0) rows_s[u] = row;
    qs[u][d] = Qb[(size_t)row * Dn + d];
    ks[u][d] = Kb[(size_t)row * Dn + d];
    vs[u][d] = Vb[(size_t)row * Dn + d];
  }
  __syncthreads();

  // pass 1: scores[u][l] = 0.0625*(Qsel[u].K[l] + Q[l].Ksel[u]), causal mask l>row
  float acc[UC][4];
#pragma unroll
  for (int u = 0; u < UC; u++)
#pragma unroll
    for (int j = 0; j < 4; j++) acc[u][j] = 0.f;

  for (int tt = 0; tt < 4; tt++) {
    float4 kk[4][4], qq[4][4];    // [j][ts] — 32 loads issued before use
#pragma unroll
    for (int j = 0; j < 4; j++) {
      int l = tid + j * 512;
      const float4* kp = (const float4*)(Kb + (size_t)l * Dn) + tt * 4;
      const float4* qp = (const float4*)(Qb + (size_t)l * Dn) + tt * 4;
#pragma unroll
      for (int ts = 0; ts < 4; ts++) { kk[j][ts] = kp[ts]; qq[j][ts] = qp[ts]; }
    }
#pragma unroll
    for (int ts = 0; ts < 4; ts++) {
      int t = tt * 4 + ts;
#pragma unroll
      for (int u = 0; u < UC; u++) {
        float4 q4 = *(const float4*)(&qs[u][t * 4]);
        float4 k4 = *(const float4*)(&ks[u][t * 4]);
#pragma unroll
        for (int j = 0; j < 4; j++) {
          acc[u][j] += q4.x * kk[j][ts].x + q4.y * kk[j][ts].y
                     + q4.z * kk[j][ts].z + q4.w * kk[j][ts].w
                     + k4.x * qq[j][ts].x + k4.y * qq[j][ts].y
                     + k4.z * qq[j][ts].z + k4.w * qq[j][ts].w;
        }
      }
    }
  }
#pragma unroll
  for (int u = 0; u < UC; u++) {
    int row = rows_s[u];
#pragma unroll
    for (int j = 0; j < 4; j++) {
      int l = tid + j * 512;
      sc[u][l] = (l > row) ? -1e9f : acc[u][j] * 0.0625f;
    }
  }
  __syncthreads();

  // pass 2: softmax per u; wave w handles u=w (waves 0..4)
  int w = tid >> 6, lane = tid & 63;
  if (w < UC) {
    float mx = -INFINITY;
    for (int kq = 0; kq < 32; kq++) mx = fmaxf(mx, sc[w][lane + 64 * kq]);
    for (int off = 32; off; off >>= 1) mx = fmaxf(mx, __shfl_xor(mx, off, 64));
    float sum = 0.f;
    for (int kq = 0; kq < 32; kq++) {
      float e = __expf(sc[w][lane + 64 * kq] - mx);
      sc[w][lane + 64 * kq] = e;
      sum += e;
    }
    for (int off = 32; off; off >>= 1) sum += __shfl_xor(sum, off, 64);
    if (lane == 0) inv_s[w] = 1.0f / sum;
  }
  __syncthreads();

  // pass 3: attn @ V ; wave w owns l in [w*256, w*256+256) for ALL 5 u.
  {
    int quad = lane & 15, lr = lane >> 4;
    int l0w = w * 256;
    const float4* V4 = (const float4*)Vb;
    float4 a[UC];
#pragma unroll
    for (int u = 0; u < UC; u++) a[u] = make_float4(0.f, 0.f, 0.f, 0.f);
    for (int it4 = 0; it4 < 16; it4++) {
      int lb = l0w + lr + it4 * 16;
      float4 v0 = V4[(size_t)(lb)      * 16 + quad];
      float4 v1 = V4[(size_t)(lb + 4)  * 16 + quad];
      float4 v2 = V4[(size_t)(lb + 8)  * 16 + quad];
      float4 v3 = V4[(size_t)(lb + 12) * 16 + quad];
#pragma unroll
      for (int u = 0; u < UC; u++) {
        float s0 = sc[u][lb], s1 = sc[u][lb + 4], s2 = sc[u][lb + 8], s3 = sc[u][lb + 12];
        a[u].x += s0 * v0.x + s1 * v1.x + s2 * v2.x + s3 * v3.x;
        a[u].y += s0 * v0.y + s1 * v1.y + s2 * v2.y + s3 * v3.y;
        a[u].z += s0 * v0.z + s1 * v1.z + s2 * v2.z + s3 * v3.z;
        a[u].w += s0 * v0.w + s1 * v1.w + s2 * v2.w + s3 * v3.w;
      }
    }
#pragma unroll
    for (int u = 0; u < UC; u++) {
#pragma unroll
      for (int off = 16; off < 64; off <<= 1) {
        a[u].x += __shfl_xor(a[u].x, off, 64);
        a[u].y += __shfl_xor(a[u].y, off, 64);
        a[u].z += __shfl_xor(a[u].z, off, 64);
        a[u].w += __shfl_xor(a[u].w, off, 64);
      }
      if (lr == 0) *(float4*)(&redp[w][u][quad * 4]) = a[u];
    }
  }
  __syncthreads();

  if (w < UC) {
    float r = 0.f;
#pragma unroll
    for (int g = 0; g < 8; g++) r += redp[g][w][lane];
    float outv = 0.5f * (vs[w][lane] + r * inv_s[w]);
    int row = rows_s[w];
    out[(((size_t)b * Ln + row) * Hn + h) * Dn + lane] = outv;
  }
}

extern "C" void kernel_launch(void* const* d_in, const int* in_sizes, int n_in,
                              void* d_out, int out_size, void* d_ws, size_t ws_size,
                              hipStream_t stream) {
  const float* Q = (const float*)d_in[0];  // (B,L,H,D) flat == (B,H,L,D) reshape
  const float* K = (const float*)d_in[1];
  const float* V = (const float*)d_in[2];
  float* out = (float*)d_out;
  char* ws = (char*)d_ws;

  float* M       = (float*)(ws + NSAMP * 4);                       // 256 KB
  int*   Mtop    = (int*)(ws + NSAMP * 4 + BHn * Ln * 4);          // 5 KB
  float* partial = (float*)(ws + NSAMP * 4 + BHn * Ln * 4 + BHn * NTOP * 4); // 256 KB

  // Partitionable threefry split of key(42) = (0,42): k2 = tf(key, ctr=(0,1)).
  uint32_t s0 = 0u, s1 = 1u;
  tf2x32(0u, 42u, s0, s1);

  compute_M<<<4096, 256, 0, stream>>>(Q, K, M, s0, s1);
  topk_fused<<<BHn, 256, 0, stream>>>(M, Mtop);
  vsum_partial<<<BHn * 32, 256, 0, stream>>>(V, partial);
  context_write<<<BHn * 32, 256, 0, stream>>>(V, partial, out);
  sparse_attn<<<BHn * 8, 512, 0, stream>>>(Q, K, V, Mtop, out);
}